// Round 3
// baseline (226.339 us; speedup 1.0000x reference)
//
#include <hip/hip_runtime.h>
#include <stdint.h>

// Problem constants (B=8, T=2048, D=256, K=8192)
#define M_TOK 16384
#define DIM   256
#define KCB   8192
#define NSPLIT 64                  // KCB / 128
#define INV_N (1.0f / 4194304.0f)  // 1/(B*T*D)

typedef __attribute__((ext_vector_type(4))) float f32x4;
typedef __attribute__((ext_vector_type(8))) __bf16 bf16x8;

static __device__ __forceinline__ unsigned short f2bf(float f) {
    uint32_t x = __float_as_uint(f);
    uint32_t r = (x + 0x7fffu + ((x >> 16) & 1u)) >> 16;   // RNE
    return (unsigned short)r;
}

// Async global->LDS DMA, 16 B per lane. LDS dest is WAVE-UNIFORM base +
// lane*16 (m104/m108 caveat) — requires unpadded, lane-order-contiguous LDS.
static __device__ __forceinline__ void lds_cp16(const void* g, void* l) {
    __builtin_amdgcn_global_load_lds(
        (const __attribute__((address_space(1))) void*)g,
        (__attribute__((address_space(3))) void*)l, 16, 0, 0);
}

// ---------------------------------------------------------------- kernel 1
// xs fp32 -> bf16 (row-major [16384][256]).
__global__ void k_conv_xs(const float4* __restrict__ xs4,
                          ushort4* __restrict__ xb4) {
    int i = blockIdx.x * 256 + threadIdx.x;          // exactly M_TOK*DIM/4 threads
    float4 v = xs4[i];
    ushort4 o;
    o.x = f2bf(v.x); o.y = f2bf(v.y); o.z = f2bf(v.z); o.w = f2bf(v.w);
    xb4[i] = o;
}

// ---------------------------------------------------------------- kernel 2
// codebook fp32 -> bf16; c_half_sq[k] = 0.5*||c_k||^2 (fp32). One wave per row.
__global__ void k_conv_cb(const float4* __restrict__ cb4,
                          ushort4* __restrict__ cbb4,
                          float* __restrict__ chalf) {
    int row  = blockIdx.x * 4 + (threadIdx.x >> 6);
    int lane = threadIdx.x & 63;
    int idx  = row * 64 + lane;                      // float4 units (256 floats/row)
    float4 v = cb4[idx];
    ushort4 o;
    o.x = f2bf(v.x); o.y = f2bf(v.y); o.z = f2bf(v.z); o.w = f2bf(v.w);
    cbb4[idx] = o;
    float s = v.x * v.x + v.y * v.y + v.z * v.z + v.w * v.w;
    #pragma unroll
    for (int off = 32; off; off >>= 1) s += __shfl_xor(s, off);
    if (lane == 0) chalf[row] = 0.5f * s;
}

// ---------------------------------------------------------------- kernel 3
// 128x128-tile bf16 MFMA GEMM with fused argmin epilogue, m97-style staging:
// global_load_lds width=16 into UNPADDED [128][32] LDS tiles. Row stride
// 64 B => each wave's ds_read_b128 fragment set covers a contiguous 1 KiB
// block (conflict-free); the round-2 +8 pad was CREATING the 1.7e7 conflicts.
__global__ __launch_bounds__(256, 2) void k_gemm_argmin(
    const unsigned short* __restrict__ xb,    // [M_TOK][DIM] bf16 bits
    const unsigned short* __restrict__ cbb,   // [KCB][DIM]  bf16 bits
    const float* __restrict__ chalf,          // [KCB]
    float* __restrict__ pval,                 // [M_TOK][NSPLIT]
    int* __restrict__ pidx)                   // [M_TOK][NSPLIT]
{
    __shared__ __align__(16) unsigned short As[128][32];
    __shared__ __align__(16) unsigned short Bs[128][32];
    __shared__ float sv[128][2];
    __shared__ int   si[128][2];

    const int tid   = threadIdx.x;
    const int w     = tid >> 6;       // wave 0..3
    const int l     = tid & 63;
    const int lrow  = l & 15;         // n (col) index inside 16x16 tile
    const int lquad = l >> 4;         // 0..3
    const int m0 = blockIdx.x * 128;
    const int n0 = blockIdx.y * 128;
    const int wm = (w >> 1) * 64;     // wave row offset in tile
    const int wn = (w & 1) * 64;      // wave col offset in tile

    // staging: wave w DMAs rows [32w, 32w+32) of As and Bs as two 16-row
    // chunks each; lane l supplies row 32w + (l>>2), bytes (l&3)*16.
    const int srow0 = w * 32 + (l >> 2);
    const int scol  = (l & 3) * 8;    // shorts

    f32x4 acc[4][4] = {};

    for (int kk = 0; kk < DIM; kk += 32) {
        lds_cp16(xb  + (size_t)(m0 + srow0)      * DIM + kk + scol, &As[w * 32][0]);
        lds_cp16(xb  + (size_t)(m0 + srow0 + 16) * DIM + kk + scol, &As[w * 32 + 16][0]);
        lds_cp16(cbb + (size_t)(n0 + srow0)      * DIM + kk + scol, &Bs[w * 32][0]);
        lds_cp16(cbb + (size_t)(n0 + srow0 + 16) * DIM + kk + scol, &Bs[w * 32 + 16][0]);
        __syncthreads();   // drains vmcnt -> LDS valid

        bf16x8 afr[4], bfr[4];
        #pragma unroll
        for (int rt = 0; rt < 4; rt++)
            afr[rt] = *(const bf16x8*)&As[wm + rt * 16 + lrow][lquad * 8];
        #pragma unroll
        for (int ct = 0; ct < 4; ct++)
            bfr[ct] = *(const bf16x8*)&Bs[wn + ct * 16 + lrow][lquad * 8];
        #pragma unroll
        for (int rt = 0; rt < 4; rt++)
            #pragma unroll
            for (int ct = 0; ct < 4; ct++)
                acc[rt][ct] = __builtin_amdgcn_mfma_f32_16x16x32_bf16(
                    afr[rt], bfr[ct], acc[rt][ct], 0, 0, 0);
        __syncthreads();
    }

    // ---- epilogue: per-lane argmin over its 4 cols, then lane/wave reduce
    float bv[4][4];
    int   bi[4][4];
    #pragma unroll
    for (int rt = 0; rt < 4; rt++)
        #pragma unroll
        for (int rg = 0; rg < 4; rg++) { bv[rt][rg] = 3.4e38f; bi[rt][rg] = 0; }

    #pragma unroll
    for (int ct = 0; ct < 4; ct++) {
        int code = n0 + wn + ct * 16 + lrow;
        float cs = chalf[code];
        #pragma unroll
        for (int rt = 0; rt < 4; rt++)
            #pragma unroll
            for (int rg = 0; rg < 4; rg++) {
                float s = cs - acc[rt][ct][rg];
                if (s < bv[rt][rg]) { bv[rt][rg] = s; bi[rt][rg] = code; }
            }
    }
    // reduce across the 16 lanes of a quad group (same rows, different cols)
    #pragma unroll
    for (int off = 1; off < 16; off <<= 1) {
        #pragma unroll
        for (int rt = 0; rt < 4; rt++)
            #pragma unroll
            for (int rg = 0; rg < 4; rg++) {
                float ov = __shfl_xor(bv[rt][rg], off);
                int   oi = __shfl_xor(bi[rt][rg], off);
                if (ov < bv[rt][rg] || (ov == bv[rt][rg] && oi < bi[rt][rg])) {
                    bv[rt][rg] = ov; bi[rt][rg] = oi;
                }
            }
    }
    if (lrow == 0) {
        #pragma unroll
        for (int rt = 0; rt < 4; rt++)
            #pragma unroll
            for (int rg = 0; rg < 4; rg++) {
                int rloc = wm + rt * 16 + lquad * 4 + rg;
                sv[rloc][w & 1] = bv[rt][rg];
                si[rloc][w & 1] = bi[rt][rg];
            }
    }
    __syncthreads();
    if (tid < 128) {
        float v0 = sv[tid][0], v1 = sv[tid][1];
        int   i0 = si[tid][0], i1 = si[tid][1];
        bool take1 = (v1 < v0) || (v1 == v0 && i1 < i0);
        float v = take1 ? v1 : v0;
        int   ix = take1 ? i1 : i0;
        size_t grow = (size_t)(m0 + tid);
        pval[grow * NSPLIT + blockIdx.y] = v;
        pidx[grow * NSPLIT + blockIdx.y] = ix;
    }
}

// ---------------------------------------------------------------- kernel 4
// Per row: min over 64 split partials -> final index; exact fp32 distance;
// per-block LDS reduce -> partial[blockIdx]. NO global atomics (round-1
// post-mortem: 16384 same-address atomicAdds serialized -> 211 us).
__global__ void k_finalize(const float* __restrict__ pval,
                           const int* __restrict__ pidx,
                           const float4* __restrict__ xs4,
                           const float4* __restrict__ cb4,
                           float* __restrict__ partial) {
    __shared__ float sblk[4];
    int w   = threadIdx.x >> 6;
    int row = blockIdx.x * 4 + w;
    int l   = threadIdx.x & 63;
    float v = pval[(size_t)row * NSPLIT + l];
    int  ix = pidx[(size_t)row * NSPLIT + l];
    #pragma unroll
    for (int off = 1; off < 64; off <<= 1) {
        float ov = __shfl_xor(v, off);
        int   oi = __shfl_xor(ix, off);
        if (ov < v || (ov == v && oi < ix)) { v = ov; ix = oi; }
    }
    float4 x = xs4[(size_t)row * 64 + l];
    float4 c = cb4[(size_t)ix * 64 + l];
    float dx = x.x - c.x, dy = x.y - c.y, dz = x.z - c.z, dw = x.w - c.w;
    float s = dx * dx + dy * dy + dz * dz + dw * dw;
    #pragma unroll
    for (int off = 32; off; off >>= 1) s += __shfl_xor(s, off);
    if (l == 0) sblk[w] = s;
    __syncthreads();
    if (threadIdx.x == 0)
        partial[blockIdx.x] = sblk[0] + sblk[1] + sblk[2] + sblk[3];
}

// ---------------------------------------------------------------- kernel 5
// Single block reduces 4096 block-partials and writes the two scalars.
__global__ void k_write(const float* __restrict__ partial,
                        float* __restrict__ out) {
    __shared__ float swv[16];
    int tid = threadIdx.x;                    // 1024 threads = 16 waves
    float s = partial[tid] + partial[tid + 1024] +
              partial[tid + 2048] + partial[tid + 3072];
    #pragma unroll
    for (int off = 32; off; off >>= 1) s += __shfl_xor(s, off);
    if ((tid & 63) == 0) swv[tid >> 6] = s;
    __syncthreads();
    if (tid == 0) {
        float t = 0.0f;
        #pragma unroll
        for (int i = 0; i < 16; i++) t += swv[i];
        float commit = t * INV_N;
        out[0] = 0.25f * commit;   // loss
        out[1] = commit;           // commit_loss
    }
}

extern "C" void kernel_launch(void* const* d_in, const int* in_sizes, int n_in,
                              void* d_out, int out_size, void* d_ws, size_t ws_size,
                              hipStream_t stream) {
    const float* xs = (const float*)d_in[0];
    // d_in[1] = ilens (int64, all == T) -> slice is a no-op, unused
    const float* cb = (const float*)d_in[2];

    char* ws = (char*)d_ws;
    unsigned short* xb      = (unsigned short*)(ws + 256);              // 8 MiB
    unsigned short* cbb     = (unsigned short*)(ws + 256 + 8388608);    // 4 MiB
    float*          chalf   = (float*)(ws + 256 + 12582912);            // 32 KiB
    float*          pval    = (float*)(ws + 256 + 12615680);            // 4 MiB
    int*            pidx    = (int*)  (ws + 256 + 16809984);            // 4 MiB
    float*          partial = (float*)(ws + 256 + 21004288);            // 16 KiB

    k_conv_xs<<<4096, 256, 0, stream>>>((const float4*)xs, (ushort4*)xb);
    k_conv_cb<<<2048, 256, 0, stream>>>((const float4*)cb, (ushort4*)cbb, chalf);
    dim3 g(M_TOK / 128, KCB / 128);
    k_gemm_argmin<<<g, 256, 0, stream>>>(xb, cbb, chalf, pval, pidx);
    k_finalize<<<4096, 256, 0, stream>>>(pval, pidx, (const float4*)xs,
                                         (const float4*)cb, partial);
    k_write<<<1, 1024, 0, stream>>>(partial, (float*)d_out);
}

// Round 4
// 179.325 us; speedup vs baseline: 1.2622x; 1.2622x over previous
//
#include <hip/hip_runtime.h>
#include <stdint.h>

// Problem constants (B=8, T=2048, D=256, K=8192)
#define M_TOK 16384
#define DIM   256
#define KCB   8192
#define NGRP  8                    // N-groups (blocks in y)
#define GRP   1024                 // codes per group
#define SHIFT 512.0f               // positivity shift for score packing
#define INV_N (1.0f / 4194304.0f)  // 1/(B*T*D)

typedef __attribute__((ext_vector_type(4))) float f32x4;
typedef __attribute__((ext_vector_type(8))) __bf16 bf16x8;

static __device__ __forceinline__ unsigned short f2bf(float f) {
    uint32_t x = __float_as_uint(f);
    uint32_t r = (x + 0x7fffu + ((x >> 16) & 1u)) >> 16;   // RNE
    return (unsigned short)r;
}

// Async global->LDS DMA, 16 B/lane; LDS dest = wave-uniform base + lane*16.
static __device__ __forceinline__ void lds_cp16(const void* g, void* l) {
    __builtin_amdgcn_global_load_lds(
        (const __attribute__((address_space(1))) void*)g,
        (__attribute__((address_space(3))) void*)l, 16, 0, 0);
}

// ---------------------------------------------------------------- kernel 1
// Merged prep: blocks [0,4096): xs -> bf16. Blocks [4096,6144): codebook ->
// NEGATED bf16 (so MFMA accumulates -x.c) and chalf = 0.5*||c||^2 + SHIFT.
__global__ void k_prep(const float4* __restrict__ xs4,
                       ushort4* __restrict__ xb4,
                       const float4* __restrict__ cb4,
                       ushort4* __restrict__ cbbn4,
                       float* __restrict__ chalf) {
    int b = blockIdx.x;
    if (b < 4096) {
        int i = b * 256 + threadIdx.x;
        float4 v = xs4[i];
        ushort4 o;
        o.x = f2bf(v.x); o.y = f2bf(v.y); o.z = f2bf(v.z); o.w = f2bf(v.w);
        xb4[i] = o;
    } else {
        b -= 4096;
        int row  = b * 4 + (threadIdx.x >> 6);
        int lane = threadIdx.x & 63;
        int idx  = row * 64 + lane;
        float4 v = cb4[idx];
        ushort4 o;                                   // store -c in bf16
        o.x = f2bf(-v.x); o.y = f2bf(-v.y); o.z = f2bf(-v.z); o.w = f2bf(-v.w);
        cbbn4[idx] = o;
        float s = v.x * v.x + v.y * v.y + v.z * v.z + v.w * v.w;
        #pragma unroll
        for (int off = 32; off; off >>= 1) s += __shfl_xor(s, off);
        if (lane == 0) chalf[row] = 0.5f * s + SHIFT;
    }
}

// ---------------------------------------------------------------- kernel 2
// Persistent-N MFMA GEMM+argmin. grid (128, 8): block = 128 rows x 1024 codes
// (8 tiles of 128). Single-barrier double-buffered staging; acc initialized
// to 0.5||c||^2+SHIFT and B = -c, so acc_final IS the (positive) score.
// Argmin kept as packed u32 key = (score_bits & ~1023) | local_code_id.
__global__ __launch_bounds__(256, 2) void k_gemm_argmin(
    const unsigned short* __restrict__ xb,     // [M_TOK][DIM] bf16
    const unsigned short* __restrict__ cbbn,   // [KCB][DIM]  bf16 of -c
    const float* __restrict__ chalf,           // [KCB] = 0.5||c||^2+SHIFT
    uint32_t* __restrict__ pkey)               // [M_TOK][NGRP]
{
    __shared__ __align__(16) unsigned short As[2][128][32];
    __shared__ __align__(16) unsigned short Bs[2][128][32];
    __shared__ __align__(16) float schalf[GRP];
    __shared__ uint32_t skey[128][2];

    const int tid   = threadIdx.x;
    const int w     = tid >> 6;
    const int l     = tid & 63;
    const int lrow  = l & 15;
    const int lquad = l >> 4;
    const int m0 = blockIdx.x * 128;
    const int g  = blockIdx.y;
    const int wm = (w >> 1) * 64;
    const int wn = (w & 1) * 64;
    const int srow0 = w * 32 + (l >> 2);
    const int scol  = (l & 3) * 8;

    // stage this group's chalf slice (4 KB) into LDS
    *(float4*)&schalf[tid * 4] = ((const float4*)(chalf + g * GRP))[tid];

    const unsigned short* Ab = xb   + (size_t)(m0 + srow0) * DIM + scol;
    const unsigned short* Bb = cbbn + (size_t)(g * GRP + srow0) * DIM + scol;

    // prefetch iter 0 into buf 0
    lds_cp16(Ab,            &As[0][w * 32][0]);
    lds_cp16(Ab + 16 * DIM, &As[0][w * 32 + 16][0]);
    lds_cp16(Bb,            &Bs[0][w * 32][0]);
    lds_cp16(Bb + 16 * DIM, &Bs[0][w * 32 + 16][0]);

    uint32_t best[4][4];
    #pragma unroll
    for (int rt = 0; rt < 4; rt++)
        #pragma unroll
        for (int rg = 0; rg < 4; rg++) best[rt][rg] = 0xFFFFFFFFu;

    __syncthreads();   // schalf + buf0 ready

    f32x4 acc[4][4];
    #pragma unroll
    for (int ct = 0; ct < 4; ct++) {           // acc init for tile 0
        float cs = schalf[wn + ct * 16 + lrow];
        #pragma unroll
        for (int rt = 0; rt < 4; rt++) {
            f32x4 c4 = {cs, cs, cs, cs};
            acc[rt][ct] = c4;
        }
    }

    #pragma unroll 2
    for (int i = 0; i < 64; i++) {
        const int buf = i & 1;
        if (i < 63) {                          // prefetch i+1 into other buf
            int ni = i + 1;
            int nt = ni >> 3, nk = ni & 7, nb = ni & 1;
            const unsigned short* An = Ab + nk * 32;
            const unsigned short* Bn = Bb + (size_t)(nt * 128) * DIM + nk * 32;
            lds_cp16(An,            &As[nb][w * 32][0]);
            lds_cp16(An + 16 * DIM, &As[nb][w * 32 + 16][0]);
            lds_cp16(Bn,            &Bs[nb][w * 32][0]);
            lds_cp16(Bn + 16 * DIM, &Bs[nb][w * 32 + 16][0]);
        }
        bf16x8 afr[4], bfr[4];
        #pragma unroll
        for (int rt = 0; rt < 4; rt++)
            afr[rt] = *(const bf16x8*)&As[buf][wm + rt * 16 + lrow][lquad * 8];
        #pragma unroll
        for (int ct = 0; ct < 4; ct++)
            bfr[ct] = *(const bf16x8*)&Bs[buf][wn + ct * 16 + lrow][lquad * 8];
        #pragma unroll
        for (int rt = 0; rt < 4; rt++)
            #pragma unroll
            for (int ct = 0; ct < 4; ct++)
                acc[rt][ct] = __builtin_amdgcn_mfma_f32_16x16x32_bf16(
                    afr[rt], bfr[ct], acc[rt][ct], 0, 0, 0);

        if ((i & 7) == 7) {                    // tile done: fold into best keys
            int t = i >> 3;
            #pragma unroll
            for (int ct = 0; ct < 4; ct++) {
                uint32_t idxl = (uint32_t)(t * 128 + wn + ct * 16 + lrow);
                #pragma unroll
                for (int rt = 0; rt < 4; rt++)
                    #pragma unroll
                    for (int rg = 0; rg < 4; rg++) {
                        uint32_t key =
                            (__float_as_uint(acc[rt][ct][rg]) & 0xFFFFFC00u) | idxl;
                        if (key < best[rt][rg]) best[rt][rg] = key;
                    }
            }
            if (i < 63) {                      // acc re-init for tile t+1
                #pragma unroll
                for (int ct = 0; ct < 4; ct++) {
                    float cs = schalf[(t + 1) * 128 + wn + ct * 16 + lrow];
                    #pragma unroll
                    for (int rt = 0; rt < 4; rt++) {
                        f32x4 c4 = {cs, cs, cs, cs};
                        acc[rt][ct] = c4;
                    }
                }
            }
        }
        __syncthreads();   // drains prefetch DMA (issued ~full compute ago)
    }

    // cross-lane min over the 16 cols held by the lquad group
    #pragma unroll
    for (int off = 1; off < 16; off <<= 1)
        #pragma unroll
        for (int rt = 0; rt < 4; rt++)
            #pragma unroll
            for (int rg = 0; rg < 4; rg++) {
                uint32_t o = __shfl_xor(best[rt][rg], off);
                if (o < best[rt][rg]) best[rt][rg] = o;
            }
    if (lrow == 0) {
        #pragma unroll
        for (int rt = 0; rt < 4; rt++)
            #pragma unroll
            for (int rg = 0; rg < 4; rg++)
                skey[wm + rt * 16 + lquad * 4 + rg][w & 1] = best[rt][rg];
    }
    __syncthreads();
    if (tid < 128) {
        uint32_t k0 = skey[tid][0], k1 = skey[tid][1];
        pkey[(size_t)(m0 + tid) * NGRP + g] = k0 < k1 ? k0 : k1;
    }
}

// ---------------------------------------------------------------- kernel 3
// Per row: min over 8 group keys -> final code; exact fp32 ||x-c||^2;
// per-block LDS reduce -> partial[blockIdx]. No global atomics.
__global__ void k_finalize(const uint32_t* __restrict__ pkey,
                           const float4* __restrict__ xs4,
                           const float4* __restrict__ cb4,
                           float* __restrict__ partial) {
    __shared__ float sblk[4];
    int w   = threadIdx.x >> 6;
    int row = blockIdx.x * 4 + w;
    int l   = threadIdx.x & 63;
    uint32_t k = 0xFFFFFFFFu;
    int g = 0;
    if (l < 8) { k = pkey[(size_t)row * NGRP + l]; g = l; }
    #pragma unroll
    for (int off = 1; off < 8; off <<= 1) {
        uint32_t ok = __shfl_xor(k, off);
        int      og = __shfl_xor(g, off);
        if (ok < k) { k = ok; g = og; }
    }
    k = __shfl(k, 0);
    g = __shfl(g, 0);
    int code = g * GRP + (int)(k & 1023u);
    float4 x = xs4[(size_t)row * 64 + l];
    float4 c = cb4[(size_t)code * 64 + l];
    float dx = x.x - c.x, dy = x.y - c.y, dz = x.z - c.z, dw = x.w - c.w;
    float s = dx * dx + dy * dy + dz * dz + dw * dw;
    #pragma unroll
    for (int off = 32; off; off >>= 1) s += __shfl_xor(s, off);
    if (l == 0) sblk[w] = s;
    __syncthreads();
    if (threadIdx.x == 0)
        partial[blockIdx.x] = sblk[0] + sblk[1] + sblk[2] + sblk[3];
}

// ---------------------------------------------------------------- kernel 4
__global__ void k_write(const float* __restrict__ partial,
                        float* __restrict__ out) {
    __shared__ float swv[16];
    int tid = threadIdx.x;                    // 1024 threads = 16 waves
    float s = partial[tid] + partial[tid + 1024] +
              partial[tid + 2048] + partial[tid + 3072];
    #pragma unroll
    for (int off = 32; off; off >>= 1) s += __shfl_xor(s, off);
    if ((tid & 63) == 0) swv[tid >> 6] = s;
    __syncthreads();
    if (tid == 0) {
        float t = 0.0f;
        #pragma unroll
        for (int i = 0; i < 16; i++) t += swv[i];
        float commit = t * INV_N;
        out[0] = 0.25f * commit;   // loss
        out[1] = commit;           // commit_loss
    }
}

extern "C" void kernel_launch(void* const* d_in, const int* in_sizes, int n_in,
                              void* d_out, int out_size, void* d_ws, size_t ws_size,
                              hipStream_t stream) {
    const float* xs = (const float*)d_in[0];
    // d_in[1] = ilens (int64, all == T) -> slice is a no-op, unused
    const float* cb = (const float*)d_in[2];

    char* ws = (char*)d_ws;
    unsigned short* xb      = (unsigned short*)(ws + 256);              // 8 MiB
    unsigned short* cbbn    = (unsigned short*)(ws + 256 + 8388608);    // 4 MiB
    float*          chalf   = (float*)(ws + 256 + 12582912);            // 32 KiB
    uint32_t*       pkey    = (uint32_t*)(ws + 256 + 12615680);         // 512 KiB
    float*          partial = (float*)(ws + 256 + 13139968);            // 16 KiB

    k_prep<<<6144, 256, 0, stream>>>((const float4*)xs, (ushort4*)xb,
                                     (const float4*)cb, (ushort4*)cbbn, chalf);
    dim3 g(M_TOK / 128, NGRP);
    k_gemm_argmin<<<g, 256, 0, stream>>>(xb, cbbn, chalf, pkey);
    k_finalize<<<4096, 256, 0, stream>>>(pkey, (const float4*)xs,
                                         (const float4*)cb, partial);
    k_write<<<1, 1024, 0, stream>>>(partial, (float*)d_out);
}